// Round 9
// baseline (963.282 us; speedup 1.0000x reference)
//
#include <hip/hip_runtime.h>
#include <hip/hip_bf16.h>

#define B_TOT 1024
#define L_T   128
#define DIN   5
#define HD    64
#define RESN  256
#define BDN   8
#define NMAT  9
#define NMAT_REG 3                          // B1, B2[0], B2[1] in VGPRs
#define NMAT_LDS 6                          // B2[2..7] in LDS
#define NROWS (NMAT * RESN)                 // 2304
#define PLANE ((size_t)NROWS * RESN)        // 589824 elems per weight plane
#define NGRP  16
#define BG    64                            // batch per group
#define FPB   16                            // features per block
#define NTHR  256                           // 4 waves = 4 independent mt-planes
#define RB_GRP (2 * BG * RESN)              // 32768 dwords per group (2 bufs)
#define WS_RB_OFF  (2 * PLANE * 2)          // bytes: after weight planes

typedef __attribute__((ext_vector_type(8))) short bf16x8;
typedef __attribute__((ext_vector_type(4))) float f32x4;

__device__ __forceinline__ float fast_tanh(float x) {
    float e = __expf(2.0f * x);
    return 1.0f - 2.0f * __builtin_amdgcn_rcpf(e + 1.0f);
}

// pack r as bf16 hi | bf16 lo, with lo's 2 LSB mantissa bits (bits 16-17 of the
// dword) replaced by a step tag -> the exchange data is self-validating.
__device__ __forceinline__ unsigned pack_hilo_tag(float v, unsigned tag16) {
    __hip_bfloat16 hi = __float2bfloat16(v);
    __hip_bfloat16 lo = __float2bfloat16(v - __bfloat162float(hi));
    unsigned pv = (unsigned)__builtin_bit_cast(unsigned short, hi) |
                  ((unsigned)__builtin_bit_cast(unsigned short, lo) << 16);
    return (pv & 0xFFFCFFFFu) | tag16;
}

// MALL-coherent accesses (bypass L1/L2 caching of the exchange region).
__device__ __forceinline__ uint4 mall_load4(const unsigned* p) {
    uint4 r;
    asm volatile("global_load_dwordx4 %0, %1, off sc0 sc1" : "=v"(r) : "v"(p));
    return r;
}
__device__ __forceinline__ void mall_store1(unsigned* p, unsigned v) {
    asm volatile("global_store_dword %0, %1, off sc0 sc1" :: "v"(p), "v"(v) : "memory");
}
__device__ __forceinline__ void wait_vm0() {
    asm volatile("s_waitcnt vmcnt(0)" ::: "memory");
}

// unpack 8 packed dwords -> hi/lo bf16x8 A-frags; mask the tag bits out of lo
__device__ __forceinline__ void unpack_af(const uint4 a, const uint4 b,
                                          bf16x8& afh, bf16x8& afl) {
    unsigned hw[4], lw[4];
    hw[0] = __builtin_amdgcn_perm(a.y, a.x, 0x05040100u);
    hw[1] = __builtin_amdgcn_perm(a.w, a.z, 0x05040100u);
    hw[2] = __builtin_amdgcn_perm(b.y, b.x, 0x05040100u);
    hw[3] = __builtin_amdgcn_perm(b.w, b.z, 0x05040100u);
    lw[0] = __builtin_amdgcn_perm(a.y, a.x, 0x07060302u) & 0xFFFCFFFCu;
    lw[1] = __builtin_amdgcn_perm(a.w, a.z, 0x07060302u) & 0xFFFCFFFCu;
    lw[2] = __builtin_amdgcn_perm(b.y, b.x, 0x07060302u) & 0xFFFCFFFCu;
    lw[3] = __builtin_amdgcn_perm(b.w, b.z, 0x07060302u) & 0xFFFCFFFCu;
    afh = __builtin_bit_cast(bf16x8, *(__attribute__((ext_vector_type(4))) unsigned*)hw);
    afl = __builtin_bit_cast(bf16x8, *(__attribute__((ext_vector_type(4))) unsigned*)lw);
}

__global__ void conv_w(const float* __restrict__ B1, const float* __restrict__ B2,
                       __hip_bfloat16* __restrict__ wh, __hip_bfloat16* __restrict__ wl) {
    int idx = blockIdx.x * 256 + threadIdx.x;
    float v = (idx < RESN * RESN) ? B1[idx] : B2[idx - RESN * RESN];
    __hip_bfloat16 h = __float2bfloat16(v);
    wh[idx] = h;
    wl[idx] = __float2bfloat16(v - __bfloat162float(h));
}

// init exchange buffers so the poison never aliases a valid tag:
// buf0 holds even-step r (tags {0,2}) -> init tag 1; buf1 odd (tags {1,3}) -> tag 0.
__global__ void init_rb(unsigned* __restrict__ rbu) {
    unsigned idx = blockIdx.x * 256 + threadIdx.x;       // total NGRP*RB_GRP = 524288
    unsigned buf = (idx & (RB_GRP - 1)) >> 14;           // BG*RESN = 16384 = 2^14
    rbu[idx] = buf ? 0x00000000u : 0x00010000u;
}

// Weight-stationary persistent kernel. 256 blocks (1/CU), 16 groups x 16 blocks.
// 4 waves = 4 independent mt-planes, NO barriers / NO flags in the main loop:
// the r-exchange dwords carry a 2-bit step tag; consumers poll the data itself
// (single MALL round trip). 3 mats' B-frags live in VGPRs, 6 in LDS.
__global__ __launch_bounds__(NTHR, 1) void sde_ws(
    const float* __restrict__ Vn,  const float* __restrict__ inc,
    const float* __restrict__ W1,  const float* __restrict__ b1,
    const float* __restrict__ W2,  const float* __restrict__ b2,
    const float* __restrict__ rho1p, const float* __restrict__ rho2p,
    const float* __restrict__ rho3p, const float* __restrict__ rho4p,
    const float* __restrict__ rho5p,
    const float* __restrict__ lam1, const float* __restrict__ lam2,
    const float* __restrict__ Wr,  const float* __restrict__ brp,
    const __hip_bfloat16* __restrict__ wbf,   // hi plane; lo at +PLANE
    unsigned int* __restrict__ rbu,
    float* __restrict__ out)
{
    __shared__ __align__(16) short wlds[2][NMAT_LDS][8][64][8];   // 98,304 B
    __shared__ __align__(16) short wrlds[2][8][4][8];             // 1,024 B
    __shared__ __align__(16) short zfrag[8];

    const int tid  = threadIdx.x;
    const int mt   = tid >> 6;       // wave = mt-plane (batch 16mt..16mt+15)
    const int lane = tid & 63;
    const int n16  = lane & 15;
    const int quad = lane >> 4;
    const int bx   = blockIdx.x;
    const int g    = ((bx & 7) << 1) | (bx >> 7);   // perf-only XCD grouping
    const int fb   = (bx >> 3) & 15;
    const int f0   = fb * FPB;
    const int b0g  = g * BG;
    unsigned int* rbg = rbu + (size_t)g * RB_GRP;

    const float rho1 = rho1p[0], rho2 = rho2p[0], rho3 = rho3p[0],
                rho4 = rho4p[0], rho5 = rho5p[0];
    const float brv = brp[0];

    // ---- phase A: h = tanh(Vn@W1^T+b1) into LDS overlay ----
    float* hf  = (float*)&wlds[0][0][0][0][0];   // [64][66]
    float* vsh = hf + 64 * 66;                   // [64][16]
    for (int p = tid; p < BG * HD; p += NTHR) {
        int b = p >> 6, hh = p & 63;
        float s = b1[hh];
        #pragma unroll
        for (int d = 0; d < DIN; ++d) s += Vn[(b0g + b) * DIN + d] * W1[hh * DIN + d];
        hf[b * 66 + hh] = fast_tanh(s);
    }
    __syncthreads();
    // ---- phase B: V slice, wave-aligned; publish r0 with tag 0 ----
    {
        int b = 16 * mt + (lane >> 2);
        #pragma unroll
        for (int i = 0; i < 4; ++i) {
            int f = (lane & 3) * 4 + i;
            float s = b2[f0 + f];
            #pragma unroll 8
            for (int hh = 0; hh < HD; ++hh) s += hf[b * 66 + hh] * W2[(f0 + f) * HD + hh];
            vsh[b * 16 + f] = s;
            mall_store1(&rbg[(0 * BG + b) * RESN + f0 + f], pack_hilo_tag(s, 0u));
        }
    }
    // ---- phase C: per-lane state (wave-local reads of vsh) ----
    float rmast[4];   // fp32 master r: batch = 16mt+4quad+rg, feature = f0+n16
    #pragma unroll
    for (int rg = 0; rg < 4; ++rg) rmast[rg] = vsh[(16 * mt + 4 * quad + rg) * 16 + n16];
    const float l1c = lam1[f0 + n16];
    float l2c[BDN];
    #pragma unroll
    for (int k = 0; k < BDN; ++k) l2c[k] = lam2[k * RESN + f0 + n16];
    __syncthreads();   // all vsh/hf reads done before weight overwrite

    // ---- phase D: reg-resident B-frags (3 mats) + LDS slice (6 mats) + Wr ----
    bf16x8 Brh[NMAT_REG][8], Brl[NMAT_REG][8];
    #pragma unroll
    for (int nt = 0; nt < NMAT_REG; ++nt)
        #pragma unroll
        for (int kk = 0; kk < 8; ++kk) {
            const size_t a = (size_t)(nt * RESN + f0 + n16) * RESN + kk * 32 + quad * 8;
            Brh[nt][kk] = *(const bf16x8*)(wbf + a);
            Brl[nt][kk] = *(const bf16x8*)(wbf + PLANE + a);
        }
    for (int e = tid; e < 2 * NMAT_LDS * 8 * 64; e += NTHR) {
        int l  = e & 63;
        int kk = (e >> 6) & 7;
        int m  = e >> 9;                          // 0..11
        int pl = (m >= NMAT_LDS) ? 1 : 0;
        int nt = m - pl * NMAT_LDS;               // 0..5 -> global mat 3+nt
        const uint4* src = (const uint4*)(wbf + (size_t)pl * PLANE +
            (size_t)((NMAT_REG + nt) * RESN + f0 + (l & 15)) * RESN + kk * 32 + (l >> 4) * 8);
        *(uint4*)&wlds[pl][nt][kk][l][0] = *src;
    }
    for (int p = tid; p < 512; p += NTHR) {   // Wr hi/lo 1-row B-frags
        int s = p >> 3, j = p & 7;
        int pl = s >> 5, kk = (s >> 2) & 7, q = s & 3;
        float v = Wr[kk * 32 + q * 8 + j];
        __hip_bfloat16 hi = __float2bfloat16(v);
        wrlds[pl][kk][q][j] = pl ? __builtin_bit_cast(short, __float2bfloat16(v - __bfloat162float(hi)))
                                 : __builtin_bit_cast(short, hi);
    }
    if (tid < 8) zfrag[tid] = 0;
    __syncthreads();

    const short* ph = (n16 == 0) ? &wrlds[0][0][quad][0] : &zfrag[0];
    const short* pw = (n16 == 0) ? &wrlds[1][0][quad][0] : &zfrag[0];
    const int    stp = (n16 == 0) ? 4 * 8 : 0;

    // ---- main loop: no barriers, no flags ----
    for (int t = 0; t < L_T - 1; ++t) {
        // dw loads (independent of exchange) issued first
        float dwv[4][8];
        #pragma unroll
        for (int rg = 0; rg < 4; ++rg) {
            const size_t bglob = (size_t)(b0g + 16 * mt + 4 * quad + rg) * (L_T * BDN);
            const float4 d0 = *(const float4*)(inc + bglob + (size_t)(t + 1) * BDN);
            const float4 d1 = *(const float4*)(inc + bglob + (size_t)(t + 1) * BDN + 4);
            dwv[rg][0] = d0.x; dwv[rg][1] = d0.y; dwv[rg][2] = d0.z; dwv[rg][3] = d0.w;
            dwv[rg][4] = d1.x; dwv[rg][5] = d1.y; dwv[rg][6] = d1.z; dwv[rg][7] = d1.w;
            if (t == 0) {
                const float4 e0 = *(const float4*)(inc + bglob);
                const float4 e1 = *(const float4*)(inc + bglob + 4);
                dwv[rg][0] += e0.x; dwv[rg][1] += e0.y; dwv[rg][2] += e0.z; dwv[rg][3] += e0.w;
                dwv[rg][4] += e1.x; dwv[rg][5] += e1.y; dwv[rg][6] += e1.z; dwv[rg][7] += e1.w;
            }
        }
        const int cur = t & 1, nxt = cur ^ 1;
        const int lead = t & 15;
        const unsigned exp16 = ((unsigned)(t & 3)) << 16;
        const unsigned* rbc = rbg + (size_t)(cur * BG + 16 * mt + n16) * RESN + quad * 8;

        // poll-by-data: load A batch, accept when every dword's tag == t&3
        uint4 ua[16];
        {
            unsigned guard = 0;
            for (;;) {
                #pragma unroll
                for (int kk = 0; kk < 8; ++kk) {
                    ua[2 * kk]     = mall_load4(rbc + kk * 32);
                    ua[2 * kk + 1] = mall_load4(rbc + kk * 32 + 4);
                }
                wait_vm0();
                unsigned bad = 0;
                #pragma unroll
                for (int i = 0; i < 16; ++i)
                    bad |= (ua[i].x ^ exp16) | (ua[i].y ^ exp16) |
                           (ua[i].z ^ exp16) | (ua[i].w ^ exp16);
                bad &= 0x00030000u;
                if (__ballot(bad != 0) == 0ull) break;
                __builtin_amdgcn_s_sleep(1);
                if (++guard > (1u << 20)) break;   // bounded: no hang
            }
        }

        // 9 matvecs, 3-term double-bf16 (per-kk unpack frees ua pressure)
        f32x4 acc[NMAT] = {};
        f32x4 accw = {};
        #pragma unroll
        for (int kk = 0; kk < 8; ++kk) {
            bf16x8 afh, afl;
            unpack_af(ua[2 * kk], ua[2 * kk + 1], afh, afl);
            bf16x8 bh[NMAT], bl[NMAT];
            #pragma unroll
            for (int nt = 0; nt < NMAT_REG; ++nt) { bh[nt] = Brh[nt][kk]; bl[nt] = Brl[nt][kk]; }
            #pragma unroll
            for (int nt = 0; nt < NMAT_LDS; ++nt) {
                bh[NMAT_REG + nt] = *(const bf16x8*)&wlds[0][nt][kk][lane][0];
                bl[NMAT_REG + nt] = *(const bf16x8*)&wlds[1][nt][kk][lane][0];
            }
            #pragma unroll
            for (int nt = 0; nt < NMAT; ++nt)
                acc[nt] = __builtin_amdgcn_mfma_f32_16x16x32_bf16(afh, bh[nt], acc[nt], 0, 0, 0);
            #pragma unroll
            for (int nt = 0; nt < NMAT; ++nt)
                acc[nt] = __builtin_amdgcn_mfma_f32_16x16x32_bf16(afl, bh[nt], acc[nt], 0, 0, 0);
            #pragma unroll
            for (int nt = 0; nt < NMAT; ++nt)
                acc[nt] = __builtin_amdgcn_mfma_f32_16x16x32_bf16(afh, bl[nt], acc[nt], 0, 0, 0);
            if (fb == lead) {
                bf16x8 wh8 = *(const bf16x8*)(ph + kk * stp);
                bf16x8 wl8 = *(const bf16x8*)(pw + kk * stp);
                accw = __builtin_amdgcn_mfma_f32_16x16x32_bf16(afh, wh8, accw, 0, 0, 0);
                accw = __builtin_amdgcn_mfma_f32_16x16x32_bf16(afl, wh8, accw, 0, 0, 0);
                accw = __builtin_amdgcn_mfma_f32_16x16x32_bf16(afh, wl8, accw, 0, 0, 0);
            }
        }

        // combine, publish tagged slice (no ack, no flag)
        const unsigned tag16 = ((unsigned)((t + 1) & 3)) << 16;
        #pragma unroll
        for (int rg = 0; rg < 4; ++rg) {
            const int bl_ = 16 * mt + 4 * quad + rg;
            float drift = fast_tanh(rho1 * acc[0][rg] + rho2 * l1c);
            float s = 0.0f;
            #pragma unroll
            for (int k = 0; k < BDN; ++k)
                s += fast_tanh(rho3 * acc[1 + k][rg] + rho4 * l2c[k]) * dwv[rg][k];
            float rn = rmast[rg] + drift + rho5 * s;
            rmast[rg] = rn;
            mall_store1(&rbg[(nxt * BG + bl_) * RESN + f0 + n16], pack_hilo_tag(rn, tag16));
        }

        // out column t: rotating leader, after r publication
        if (fb == lead && n16 == 0) {
            #pragma unroll
            for (int rg = 0; rg < 4; ++rg)
                out[(size_t)(b0g + 16 * mt + 4 * quad + rg) * L_T + t] = accw[rg] + brv;
        }
    }

    // ---- final column t = 127 (leader fb==15; r_127 in buf 1, tag 127&3=3) ----
    if (fb == 15) {
        const unsigned exp16 = 3u << 16;
        const unsigned* rbc = rbg + (size_t)(1 * BG + 16 * mt + n16) * RESN + quad * 8;
        uint4 ua[16];
        unsigned guard = 0;
        for (;;) {
            #pragma unroll
            for (int kk = 0; kk < 8; ++kk) {
                ua[2 * kk]     = mall_load4(rbc + kk * 32);
                ua[2 * kk + 1] = mall_load4(rbc + kk * 32 + 4);
            }
            wait_vm0();
            unsigned bad = 0;
            #pragma unroll
            for (int i = 0; i < 16; ++i)
                bad |= (ua[i].x ^ exp16) | (ua[i].y ^ exp16) |
                       (ua[i].z ^ exp16) | (ua[i].w ^ exp16);
            bad &= 0x00030000u;
            if (__ballot(bad != 0) == 0ull) break;
            __builtin_amdgcn_s_sleep(1);
            if (++guard > (1u << 20)) break;
        }
        f32x4 accw = {};
        #pragma unroll
        for (int kk = 0; kk < 8; ++kk) {
            bf16x8 afh, afl;
            unpack_af(ua[2 * kk], ua[2 * kk + 1], afh, afl);
            bf16x8 wh8 = *(const bf16x8*)(ph + kk * stp);
            bf16x8 wl8 = *(const bf16x8*)(pw + kk * stp);
            accw = __builtin_amdgcn_mfma_f32_16x16x32_bf16(afh, wh8, accw, 0, 0, 0);
            accw = __builtin_amdgcn_mfma_f32_16x16x32_bf16(afl, wh8, accw, 0, 0, 0);
            accw = __builtin_amdgcn_mfma_f32_16x16x32_bf16(afh, wl8, accw, 0, 0, 0);
        }
        if (n16 == 0) {
            #pragma unroll
            for (int rg = 0; rg < 4; ++rg)
                out[(size_t)(b0g + 16 * mt + 4 * quad + rg) * L_T + (L_T - 1)] = accw[rg] + brv;
        }
    }
}

extern "C" void kernel_launch(void* const* d_in, const int* in_sizes, int n_in,
                              void* d_out, int out_size, void* d_ws, size_t ws_size,
                              hipStream_t stream) {
    const float* Vn   = (const float*)d_in[0];
    const float* inc  = (const float*)d_in[1];
    const float* W1   = (const float*)d_in[2];
    const float* b1   = (const float*)d_in[3];
    const float* W2   = (const float*)d_in[4];
    const float* b2   = (const float*)d_in[5];
    const float* r1   = (const float*)d_in[6];
    const float* r2   = (const float*)d_in[7];
    const float* r3   = (const float*)d_in[8];
    const float* r4   = (const float*)d_in[9];
    const float* r5   = (const float*)d_in[10];
    const float* B1   = (const float*)d_in[11];
    const float* B2   = (const float*)d_in[12];
    const float* lam1 = (const float*)d_in[13];
    const float* lam2 = (const float*)d_in[14];
    const float* Wr   = (const float*)d_in[15];
    const float* br   = (const float*)d_in[16];

    __hip_bfloat16* wh  = (__hip_bfloat16*)d_ws;
    unsigned int*   rbu = (unsigned int*)((char*)d_ws + WS_RB_OFF);
    float* out = (float*)d_out;

    init_rb<<<dim3(NGRP * RB_GRP / 256), dim3(256), 0, stream>>>(rbu);
    conv_w<<<dim3(NROWS * RESN / 256), dim3(256), 0, stream>>>(B1, B2, wh, wh + PLANE);
    sde_ws<<<dim3(256), dim3(NTHR), 0, stream>>>(
        Vn, inc, W1, b1, W2, b2, r1, r2, r3, r4, r5, lam1, lam2, Wr, br,
        wh, rbu, out);
}